// Round 3
// baseline (334.804 us; speedup 1.0000x reference)
//
#include <hip/hip_runtime.h>
#include <math.h>

#define BATCH 32
#define CIN   128
#define DDIM  64
#define KCB   512
#define HWSZ  4096                       // 64*64
#define NPIX  (BATCH*HWSZ)               // 131072 pixels
#define NOUTQ (8388608)                  // BATCH*DDIM*HWSZ

// ---------------------------------------------------------------------------
// Prep kernel (1 block): transpose conv_w [D][C] -> wT [C][D] (uniform-read
// friendly), precompute ||c_k||^2, zero the loss slot (harness does NOT
// re-poison d_out between graph replays).
// ---------------------------------------------------------------------------
__global__ __launch_bounds__(256) void vq_prep(
    const float* __restrict__ w,      // [D][C]
    const float* __restrict__ cb,     // [K][D]
    float* __restrict__ wT,           // [C][D]
    float* __restrict__ cbn,          // [K]
    float* __restrict__ loss_slot)
{
    int t = threadIdx.x;
    for (int i = t; i < CIN * DDIM; i += 256) {
        int d = i / CIN;
        int c = i - d * CIN;
        wT[c * DDIM + d] = w[i];
    }
    for (int k = t; k < KCB; k += 256) {
        const float4* row = (const float4*)(cb + k * DDIM);
        float s = 0.f;
        #pragma unroll
        for (int i = 0; i < DDIM / 4; ++i) {
            float4 v = row[i];
            s = fmaf(v.x, v.x, s);
            s = fmaf(v.y, v.y, s);
            s = fmaf(v.z, v.z, s);
            s = fmaf(v.w, v.w, s);
        }
        cbn[k] = s;
    }
    if (t == 0) *loss_slot = 0.f;
}

// 16 named float4 registers hold z[64] — named SSA values cannot be demoted
// to scratch (round-1's float z[64] array was: VGPR_Count=44 < 64).
#define APPLY16(M) M(0) M(1) M(2) M(3) M(4) M(5) M(6) M(7) \
                   M(8) M(9) M(10) M(11) M(12) M(13) M(14) M(15)

__global__ __launch_bounds__(256, 4) void vq_main(
    const float* __restrict__ x,      // [B][C][HW]
    const float* __restrict__ bias,   // [D]
    const float* __restrict__ cb,     // [K][D]
    const float* __restrict__ wT,     // [C][D]
    const float* __restrict__ cbn,    // [K]
    float* __restrict__ out,          // [B][D][HW]
    float* __restrict__ loss_slot)
{
    const int p  = blockIdx.x * 256 + threadIdx.x;   // pixel id
    const int b  = p >> 12;                          // / 4096
    const int hw = p & 4095;
    const float* xp = x + ((size_t)b * CIN) * HWSZ + hw;

    // ---- z init from bias (uniform loads) ----
    const float4* bz = (const float4*)bias;
    #define ZINIT(i) float4 z##i = bz[i];
    APPLY16(ZINIT)

    // ---- projection: z[d] += sum_c x[c] * wT[c][d] ----
    // Per z-element the fmaf chain runs c=0,1,2,... in order — identical FP
    // order to the passing round-1 kernel (argmin decisions must bit-match).
    for (int c = 0; c < CIN; c += 2) {
        float xa = xp[(size_t)c * HWSZ];             // coalesced
        float xb = xp[(size_t)(c + 1) * HWSZ];
        const float4* wra = (const float4*)(wT + c * DDIM);        // uniform
        const float4* wrb = (const float4*)(wT + (c + 1) * DDIM);  // uniform
        #define PSTEP(i) { \
            float4 wv = wra[i]; \
            z##i.x = fmaf(xa, wv.x, z##i.x); z##i.y = fmaf(xa, wv.y, z##i.y); \
            z##i.z = fmaf(xa, wv.z, z##i.z); z##i.w = fmaf(xa, wv.w, z##i.w); \
            float4 wu = wrb[i]; \
            z##i.x = fmaf(xb, wu.x, z##i.x); z##i.y = fmaf(xb, wu.y, z##i.y); \
            z##i.z = fmaf(xb, wu.z, z##i.z); z##i.w = fmaf(xb, wu.w, z##i.w); }
        APPLY16(PSTEP)
        #undef PSTEP
    }

    // ---- ||z||^2, sequential d=0..63 (same order as round 1) ----
    float znorm = 0.f;
    #define NSTEP(i) { \
        znorm = fmaf(z##i.x, z##i.x, znorm); znorm = fmaf(z##i.y, z##i.y, znorm); \
        znorm = fmaf(z##i.z, z##i.z, znorm); znorm = fmaf(z##i.w, z##i.w, znorm); }
    APPLY16(NSTEP)
    #undef NSTEP

    // ---- nearest codebook entry; k unrolled x2, two independent 16-FMA
    //      chains for ILP (we sit at 2 waves/SIMD, grid-limited).
    //      Per-code dot order + dist expression identical to round 1;
    //      cascaded strict-< compares preserve ascending-k argmin. ----
    float best = INFINITY;
    int bestk = 0;
    for (int k = 0; k < KCB; k += 2) {
        const float4* ca = (const float4*)(cb + (size_t)k * DDIM);        // uniform
        const float4* cbr = (const float4*)(cb + (size_t)(k + 1) * DDIM); // uniform
        float da = 0.f, db = 0.f;
        #define DSTEP(i) { \
            float4 va = ca[i]; \
            da = fmaf(z##i.x, va.x, da); da = fmaf(z##i.y, va.y, da); \
            da = fmaf(z##i.z, va.z, da); da = fmaf(z##i.w, va.w, da); \
            float4 vb = cbr[i]; \
            db = fmaf(z##i.x, vb.x, db); db = fmaf(z##i.y, vb.y, db); \
            db = fmaf(z##i.z, vb.z, db); db = fmaf(z##i.w, vb.w, db); }
        APPLY16(DSTEP)
        #undef DSTEP
        float dista = znorm - 2.f * da + cbn[k];
        float distb = znorm - 2.f * db + cbn[k + 1];
        if (dista < best) { best = dista; bestk = k; }
        if (distb < best) { best = distb; bestk = k + 1; }
    }

    // ---- gather winner, store (coalesced per d-plane), loss partial ----
    const float4* qrow = (const float4*)(cb + (size_t)bestk * DDIM);  // divergent, L2-hot
    float lsum = 0.f;
    size_t obase = ((size_t)b * DDIM) * HWSZ + hw;
    #define OSTEP(i) { \
        float4 qv = qrow[i]; \
        float e0 = qv.x - z##i.x; float e1 = qv.y - z##i.y; \
        float e2 = qv.z - z##i.z; float e3 = qv.w - z##i.w; \
        lsum = fmaf(e0, e0, lsum); lsum = fmaf(e1, e1, lsum); \
        lsum = fmaf(e2, e2, lsum); lsum = fmaf(e3, e3, lsum); \
        out[obase + (size_t)(4 * i + 0) * HWSZ] = qv.x; \
        out[obase + (size_t)(4 * i + 1) * HWSZ] = qv.y; \
        out[obase + (size_t)(4 * i + 2) * HWSZ] = qv.z; \
        out[obase + (size_t)(4 * i + 3) * HWSZ] = qv.w; }
    APPLY16(OSTEP)
    #undef OSTEP

    // wave-level reduce (64 lanes), one atomic per wave
    #pragma unroll
    for (int off = 32; off > 0; off >>= 1)
        lsum += __shfl_down(lsum, off, 64);
    if ((threadIdx.x & 63) == 0)
        atomicAdd(loss_slot, lsum * (1.25f / (float)NOUTQ));
}

extern "C" void kernel_launch(void* const* d_in, const int* in_sizes, int n_in,
                              void* d_out, int out_size, void* d_ws, size_t ws_size,
                              hipStream_t stream) {
    const float* x    = (const float*)d_in[0];   // [32,128,64,64]
    const float* w    = (const float*)d_in[1];   // [64,128]
    const float* bias = (const float*)d_in[2];   // [64]
    const float* cb   = (const float*)d_in[3];   // [512,64]
    float* out = (float*)d_out;                  // 8388608 quantized + 1 loss
    float* wT  = (float*)d_ws;                   // [128][64]
    float* cbn = wT + CIN * DDIM;                // [512]
    float* loss_slot = out + NOUTQ;

    vq_prep<<<1, 256, 0, stream>>>(w, cb, wT, cbn, loss_slot);
    vq_main<<<NPIX / 256, 256, 0, stream>>>(x, bias, cb, wT, cbn, out, loss_slot);
}

// Round 4
// 251.603 us; speedup vs baseline: 1.3307x; 1.3307x over previous
//
#include <hip/hip_runtime.h>
#include <math.h>

#define CIN   128
#define DDIM  64
#define KCB   512
#define HWSZ  4096
#define NPIX  131072
#define NOUTQ 8388608
#define CHUNK 64             // codes per staged LDS chunk (16 KB)
#define NCHUNK (KCB/CHUNK)   // 8

// ---------------------------------------------------------------------------
// Prep: transpose conv_w -> wT [C][D], precompute ||c_k||^2 (same FP order as
// round 1 -> bit-identical), zero loss slot (harness never re-poisons d_out).
// ---------------------------------------------------------------------------
__global__ __launch_bounds__(256) void vq_prep(
    const float* __restrict__ w,      // [D][C]
    const float* __restrict__ cb,     // [K][D]
    float* __restrict__ wT,           // [C][D]
    float* __restrict__ cbn,          // [K]
    float* __restrict__ loss_slot)
{
    int i = blockIdx.x * 256 + threadIdx.x;
    if (i < CIN * DDIM) {
        int c = i >> 6, d = i & 63;
        wT[i] = w[d * CIN + c];                 // coalesced write
    } else if (i < CIN * DDIM + KCB) {
        int k = i - CIN * DDIM;
        const float4* row = (const float4*)(cb + (size_t)k * DDIM);
        float s = 0.f;
        #pragma unroll
        for (int j = 0; j < DDIM / 4; ++j) {
            float4 v = row[j];
            s = fmaf(v.x, v.x, s); s = fmaf(v.y, v.y, s);
            s = fmaf(v.z, v.z, s); s = fmaf(v.w, v.w, s);
        }
        cbn[k] = s;
    } else if (i == CIN * DDIM + KCB) {
        *loss_slot = 0.f;
    }
}

#define APPLY8(M) M(0) M(1) M(2) M(3) M(4) M(5) M(6) M(7)

// ---------------------------------------------------------------------------
// Main: 2 threads per pixel (lanes l and l^32 of a wave), 256-thr blocks.
//  - group g = lane>>5. Projection: thread computes z[d] for d in [g*32,g*32+32)
//    over ALL 128 channels (chain c=0..127 sequential == round-1 bits).
//  - halves exchanged via shfl_xor(32) -> full z in regs (16 float4).
//  - argmin: codebook staged in LDS 64-code chunks (double-buffered, reg-
//    staged prefetch); group g scans codes k==g (mod 2) ascending; combine
//    with lexicographic (dist,k) -> identical winner to full ascending scan.
//  - output/loss: each thread handles its d-half.
// ---------------------------------------------------------------------------
__global__ __launch_bounds__(256, 4) void vq_main(
    const float* __restrict__ x,      // [B][C][HW]
    const float* __restrict__ bias,   // [D]
    const float* __restrict__ cb,     // [K][D]
    const float* __restrict__ wT,     // [C][D]
    const float* __restrict__ cbn,    // [K]
    float* __restrict__ out,          // [B][D][HW]
    float* __restrict__ loss_slot)
{
    __shared__ float sU[2 * CHUNK * DDIM];   // 32 KB union: wT, then cb dbuf
    __shared__ float sCbn[KCB];              // 2 KB

    const int t  = threadIdx.x;
    const int wv = t >> 6;
    const int l  = t & 63;
    const int g  = l >> 5;                   // d-half / k-parity group
    const int pl = l & 31;
    const int pix = blockIdx.x * 128 + wv * 32 + pl;
    const int b  = pix >> 12;
    const int hw = pix & 4095;
    const float* xp = x + ((size_t)b * CIN) * HWSZ + hw;

    // ---- stage wT (32 KB) + cbn (2 KB) into LDS ----
    {
        const float4* src = (const float4*)wT;   // 2048 float4
        float4* dst = (float4*)sU;
        float4 r0 = src[t],        r1 = src[t + 256],  r2 = src[t + 512],  r3 = src[t + 768];
        float4 r4 = src[t + 1024], r5 = src[t + 1280], r6 = src[t + 1536], r7 = src[t + 1792];
        dst[t] = r0;        dst[t + 256] = r1;  dst[t + 512] = r2;  dst[t + 768] = r3;
        dst[t + 1024] = r4; dst[t + 1280] = r5; dst[t + 1536] = r6; dst[t + 1792] = r7;
        sCbn[t] = cbn[t];
        sCbn[t + 256] = cbn[t + 256];
    }
    __syncthreads();

    // ---- projection: my 32 d's (a0..a7), chain c = 0..127 sequential ----
    const float4* bz = (const float4*)bias;
    #define AINIT(j) float4 a##j = bz[g * 8 + j];
    APPLY8(AINIT)
    #undef AINIT
    for (int c = 0; c < CIN; c += 4) {
        float x0 = xp[(size_t)(c + 0) * HWSZ];
        float x1 = xp[(size_t)(c + 1) * HWSZ];
        float x2 = xp[(size_t)(c + 2) * HWSZ];
        float x3 = xp[(size_t)(c + 3) * HWSZ];
        const float4* w0 = (const float4*)(sU + (c + 0) * DDIM + g * 32);
        const float4* w1 = (const float4*)(sU + (c + 1) * DDIM + g * 32);
        const float4* w2 = (const float4*)(sU + (c + 2) * DDIM + g * 32);
        const float4* w3 = (const float4*)(sU + (c + 3) * DDIM + g * 32);
        #define PJ(j) { float4 v; \
            v = w0[j]; a##j.x = fmaf(x0, v.x, a##j.x); a##j.y = fmaf(x0, v.y, a##j.y); \
                       a##j.z = fmaf(x0, v.z, a##j.z); a##j.w = fmaf(x0, v.w, a##j.w); \
            v = w1[j]; a##j.x = fmaf(x1, v.x, a##j.x); a##j.y = fmaf(x1, v.y, a##j.y); \
                       a##j.z = fmaf(x1, v.z, a##j.z); a##j.w = fmaf(x1, v.w, a##j.w); \
            v = w2[j]; a##j.x = fmaf(x2, v.x, a##j.x); a##j.y = fmaf(x2, v.y, a##j.y); \
                       a##j.z = fmaf(x2, v.z, a##j.z); a##j.w = fmaf(x2, v.w, a##j.w); \
            v = w3[j]; a##j.x = fmaf(x3, v.x, a##j.x); a##j.y = fmaf(x3, v.y, a##j.y); \
                       a##j.z = fmaf(x3, v.z, a##j.z); a##j.w = fmaf(x3, v.w, a##j.w); }
        APPLY8(PJ)
        #undef PJ
    }
    __syncthreads();   // everyone done reading wT before cb chunks overwrite sU

    // ---- exchange halves: zl = d 0..31, zh = d 32..63 (a+b==b+a not needed:
    //      pure bit-copy via shfl; selects pick which half is own) ----
    #define MKP(j) float4 p##j; \
        p##j.x = __shfl_xor(a##j.x, 32, 64); p##j.y = __shfl_xor(a##j.y, 32, 64); \
        p##j.z = __shfl_xor(a##j.z, 32, 64); p##j.w = __shfl_xor(a##j.w, 32, 64);
    APPLY8(MKP)
    #undef MKP
    #define MKZ(j) float4 zl##j = g ? p##j : a##j; float4 zh##j = g ? a##j : p##j;
    APPLY8(MKZ)
    #undef MKZ

    // ---- ||z||^2, d = 0..63 sequential (round-1 order) ----
    float znorm = 0.f;
    #define NL(j) { znorm = fmaf(zl##j.x, zl##j.x, znorm); znorm = fmaf(zl##j.y, zl##j.y, znorm); \
                    znorm = fmaf(zl##j.z, zl##j.z, znorm); znorm = fmaf(zl##j.w, zl##j.w, znorm); }
    APPLY8(NL)
    #undef NL
    #define NH(j) { znorm = fmaf(zh##j.x, zh##j.x, znorm); znorm = fmaf(zh##j.y, zh##j.y, znorm); \
                    znorm = fmaf(zh##j.z, zh##j.z, znorm); znorm = fmaf(zh##j.w, zh##j.w, znorm); }
    APPLY8(NH)
    #undef NH

    // ---- argmin over codebook, LDS double-buffered 64-code chunks ----
    float best = INFINITY;
    int bestk = 0;
    const float4* csrc = (const float4*)cb;      // 8192 float4 total
    float4 s0 = csrc[t], s1 = csrc[t + 256], s2 = csrc[t + 512], s3 = csrc[t + 768];
    for (int ch = 0; ch < NCHUNK; ++ch) {
        float4* buf = (float4*)(sU + (ch & 1) * (CHUNK * DDIM));
        buf[t] = s0; buf[t + 256] = s1; buf[t + 512] = s2; buf[t + 768] = s3;
        __syncthreads();
        if (ch < NCHUNK - 1) {                   // prefetch next chunk -> regs
            const float4* ns = csrc + (ch + 1) * 1024;
            s0 = ns[t]; s1 = ns[t + 256]; s2 = ns[t + 512]; s3 = ns[t + 768];
        }
        const float* rbase = sU + (ch & 1) * (CHUNK * DDIM) + g * DDIM;
        #pragma unroll 1
        for (int j = 0; j < CHUNK / 2; ++j) {
            const float4* cr = (const float4*)(rbase + j * (2 * DDIM));
            float dot = 0.f;
            #define DLO(i) { float4 v = cr[i]; \
                dot = fmaf(zl##i.x, v.x, dot); dot = fmaf(zl##i.y, v.y, dot); \
                dot = fmaf(zl##i.z, v.z, dot); dot = fmaf(zl##i.w, v.w, dot); }
            APPLY8(DLO)
            #undef DLO
            #define DHI(i) { float4 v = cr[8 + i]; \
                dot = fmaf(zh##i.x, v.x, dot); dot = fmaf(zh##i.y, v.y, dot); \
                dot = fmaf(zh##i.z, v.z, dot); dot = fmaf(zh##i.w, v.w, dot); }
            APPLY8(DHI)
            #undef DHI
            int k = ch * CHUNK + 2 * j + g;
            float dist = znorm - 2.f * dot + sCbn[k];   // round-1 expression
            if (dist < best) { best = dist; bestk = k; } // ascending-k strict <
        }
    }

    // ---- combine parity groups: lexicographic (dist, k) == global first-min
    float ob = __shfl_xor(best, 32, 64);
    int   ok = __shfl_xor(bestk, 32, 64);
    if (ob < best || (ob == best && ok < bestk)) { best = ob; bestk = ok; }

    // ---- gather winner (my d-half), store, loss partial ----
    const float4* qr = (const float4*)(cb + (size_t)bestk * DDIM + g * 32);
    float lsum = 0.f;
    size_t obase = ((size_t)b * DDIM + g * 32) * HWSZ + hw;
    #define OST(j) { float4 q = qr[j]; \
        float e0 = q.x - a##j.x, e1 = q.y - a##j.y, e2 = q.z - a##j.z, e3 = q.w - a##j.w; \
        lsum = fmaf(e0, e0, lsum); lsum = fmaf(e1, e1, lsum); \
        lsum = fmaf(e2, e2, lsum); lsum = fmaf(e3, e3, lsum); \
        out[obase + (size_t)(4 * j + 0) * HWSZ] = q.x; \
        out[obase + (size_t)(4 * j + 1) * HWSZ] = q.y; \
        out[obase + (size_t)(4 * j + 2) * HWSZ] = q.z; \
        out[obase + (size_t)(4 * j + 3) * HWSZ] = q.w; }
    APPLY8(OST)
    #undef OST

    // wave reduce (covers 32 pixels x full d), one atomic per wave
    #pragma unroll
    for (int off = 32; off > 0; off >>= 1)
        lsum += __shfl_down(lsum, off, 64);
    if (l == 0)
        atomicAdd(loss_slot, lsum * (1.25f / (float)NOUTQ));
}

extern "C" void kernel_launch(void* const* d_in, const int* in_sizes, int n_in,
                              void* d_out, int out_size, void* d_ws, size_t ws_size,
                              hipStream_t stream) {
    const float* x    = (const float*)d_in[0];   // [32,128,64,64]
    const float* w    = (const float*)d_in[1];   // [64,128]
    const float* bias = (const float*)d_in[2];   // [64]
    const float* cb   = (const float*)d_in[3];   // [512,64]
    float* out = (float*)d_out;                  // 8388608 quantized + 1 loss
    float* wT  = (float*)d_ws;                   // [128][64]
    float* cbn = wT + CIN * DDIM;                // [512]
    float* loss_slot = out + NOUTQ;

    vq_prep<<<(CIN * DDIM + KCB + 1 + 255) / 256, 256, 0, stream>>>(w, cb, wT, cbn, loss_slot);
    vq_main<<<NPIX / 128, 256, 0, stream>>>(x, bias, cb, wT, cbn, out, loss_slot);
}

// Round 5
// 137.337 us; speedup vs baseline: 2.4378x; 1.8320x over previous
//
#include <hip/hip_runtime.h>
#include <math.h>

#define CIN   128
#define DDIM  64
#define KCB   512
#define HWSZ  4096
#define NPIX  131072
#define NOUTQ 8388608

typedef short bf16x8 __attribute__((ext_vector_type(8)));
typedef float f32x4  __attribute__((ext_vector_type(4)));

__device__ __forceinline__ unsigned int bcu(float f) { union { float f; unsigned int u; } v; v.f = f; return v.u; }
__device__ __forceinline__ float bcf(unsigned int u) { union { unsigned int u; float f; } v; v.u = u; return v.f; }
__device__ __forceinline__ unsigned short f2bf(float f) {   // f32 -> bf16 RNE
    unsigned int u = bcu(f);
    u += 0x7FFFu + ((u >> 16) & 1u);
    return (unsigned short)(u >> 16);
}

// Zero the loss accumulator each call (harness poisons d_out once, never re-poisons).
__global__ void vq_zero(float* loss_slot) { *loss_slot = 0.f; }

// ---------------------------------------------------------------------------
// One block per CU (grid=256, 1024 threads = 16 waves, ~150 KB LDS).
// Per block: 512 pixels in 2 iterations of 256.
// Phase A: Z[16pix x 64d] per wave via mfma_f32_16x16x32_bf16 (A=W, B=x).
// Phase B: score = ||c||^2 - 2 z.c via MFMA (A=-2c, B=z), packed-key argmin.
// Output: gather winning codebook row in f32 (exact), coalesced stores.
// Loss: 1.25 * mean((q - z_f32)^2) via wave reduce + atomics.
// ---------------------------------------------------------------------------
__global__ __launch_bounds__(1024, 4) void vq_mfma(
    const float* __restrict__ x,      // [32][128][4096]
    const float* __restrict__ w,      // [64][128]
    const float* __restrict__ bias,   // [64]
    const float* __restrict__ cb,     // [512][64]
    float* __restrict__ out,          // [32][64][4096], loss at +NOUTQ
    float* __restrict__ loss_slot)
{
    __shared__ __align__(16) unsigned short sCbA[KCB * DDIM];   // 64 KB: -2c A-frags
    __shared__ __align__(16) unsigned short sWA[DDIM * CIN];    // 16 KB: W A-frags
    __shared__ __align__(16) float sCbn[KCB];                   // 2 KB
    __shared__ __align__(16) float sBias[DDIM];                 // 256 B
    __shared__ __align__(16) unsigned short sXZ[256 * 136];     // 68 KB xT/zT union

    const int t   = threadIdx.x;
    const int l   = t & 63;
    const int wv  = t >> 6;          // wave 0..15
    const int p16 = l & 15;          // pixel-in-tile  (MFMA col = lane&15)
    const int lg  = l >> 4;          // lane group 0..3
    const int klg = lg * 4;          // row base: (lane>>4)*4

    // ================= prologue: stage frags (once per block) =================
    #pragma unroll
    for (int j = 0; j < 32; ++j) {           // codebook A-frags: A[k][d] = -2*cb
        int i = t + j * 1024;                // 32768 elems, coalesced read
        int k = i >> 6, d = i & 63;
        unsigned short v = f2bf(-2.0f * cb[i]);
        int ct = k >> 4, ks = d >> 5, lhi = (d >> 3) & 3;
        int ll = (k & 15) | (lhi << 4), e = d & 7;
        sCbA[((ct * 2 + ks) * 64 + ll) * 8 + e] = v;
    }
    #pragma unroll
    for (int j = 0; j < 8; ++j) {            // W A-frags: A[d][c]
        int i = t + j * 1024;                // 8192 elems
        int d = i >> 7, c = i & 127;
        unsigned short v = f2bf(w[i]);
        int dt = d >> 4, ks = c >> 5, lhi = (c >> 3) & 3;
        int ll = (d & 15) | (lhi << 4), e = c & 7;
        sWA[((dt * 4 + ks) * 64 + ll) * 8 + e] = v;
    }
    if (t < KCB) {                           // ||c_k||^2 (f32)
        const float4* row = (const float4*)(cb + (size_t)t * DDIM);
        float s = 0.f;
        #pragma unroll
        for (int j = 0; j < DDIM / 4; ++j) {
            float4 v = row[j];
            s = fmaf(v.x, v.x, s); s = fmaf(v.y, v.y, s);
            s = fmaf(v.z, v.z, s); s = fmaf(v.w, v.w, s);
        }
        sCbn[t] = s;
    }
    if (t < DDIM) sBias[t] = bias[t];
    __syncthreads();

    // ================= 2 iterations x 256 pixels =================
    for (int iter = 0; iter < 2; ++iter) {
        const int pixbase = blockIdx.x * 512 + iter * 256;
        const int bb  = pixbase >> 12;       // batch (uniform: 256 | 4096)
        const int hw0 = pixbase & 4095;

        // ---- stage xT: [256 pix][128 c] bf16, row stride 136 (pad kills conflicts)
        {
            const int sp = t & 255;          // pixel
            const int cg = t >> 8;           // channel group 0..3
            const float* xb = x + ((size_t)bb * CIN) * HWSZ + hw0 + sp;
            #pragma unroll
            for (int j = 0; j < 8; ++j) {
                int c = cg * 32 + j * 4;
                float v0 = xb[(size_t)(c + 0) * HWSZ];   // coalesced per lane-row
                float v1 = xb[(size_t)(c + 1) * HWSZ];
                float v2 = xb[(size_t)(c + 2) * HWSZ];
                float v3 = xb[(size_t)(c + 3) * HWSZ];
                unsigned int u0 = (unsigned int)f2bf(v0) | ((unsigned int)f2bf(v1) << 16);
                unsigned int u1 = (unsigned int)f2bf(v2) | ((unsigned int)f2bf(v3) << 16);
                unsigned int* dst = (unsigned int*)(sXZ + sp * 136 + c);
                dst[0] = u0; dst[1] = u1;    // ds_write_b64
            }
        }
        __syncthreads();

        // ---- phase A: z = W x + b  (wave: 16 pixels x 64 d, 16 MFMA) ----
        const int row = wv * 16 + p16;       // this lane's pixel row in LDS
        f32x4 za0 = *(const f32x4*)(sBias +  0 + klg);
        f32x4 za1 = *(const f32x4*)(sBias + 16 + klg);
        f32x4 za2 = *(const f32x4*)(sBias + 32 + klg);
        f32x4 za3 = *(const f32x4*)(sBias + 48 + klg);
        #pragma unroll
        for (int ks = 0; ks < 4; ++ks) {
            bf16x8 xf = *(const bf16x8*)(sXZ + row * 136 + ks * 32 + lg * 8);
            bf16x8 w0 = *(const bf16x8*)(sWA + ((0 * 4 + ks) * 64 + l) * 8);
            bf16x8 w1 = *(const bf16x8*)(sWA + ((1 * 4 + ks) * 64 + l) * 8);
            bf16x8 w2 = *(const bf16x8*)(sWA + ((2 * 4 + ks) * 64 + l) * 8);
            bf16x8 w3 = *(const bf16x8*)(sWA + ((3 * 4 + ks) * 64 + l) * 8);
            za0 = __builtin_amdgcn_mfma_f32_16x16x32_bf16(w0, xf, za0, 0, 0, 0);
            za1 = __builtin_amdgcn_mfma_f32_16x16x32_bf16(w1, xf, za1, 0, 0, 0);
            za2 = __builtin_amdgcn_mfma_f32_16x16x32_bf16(w2, xf, za2, 0, 0, 0);
            za3 = __builtin_amdgcn_mfma_f32_16x16x32_bf16(w3, xf, za3, 0, 0, 0);
        }
        __syncthreads();   // all xT reads done before zT overwrites the union

        // ---- write z (bf16) to zT, row stride 72 ----
        {
            unsigned int* zr = (unsigned int*)(sXZ + row * 72);
            #define ZW(dt, za) { \
                unsigned int uA = (unsigned int)f2bf(za[0]) | ((unsigned int)f2bf(za[1]) << 16); \
                unsigned int uB = (unsigned int)f2bf(za[2]) | ((unsigned int)f2bf(za[3]) << 16); \
                zr[(dt * 16 + klg) >> 1] = uA; zr[((dt * 16 + klg) >> 1) + 1] = uB; }
            ZW(0, za0) ZW(1, za1) ZW(2, za2) ZW(3, za3)
            #undef ZW
        }
        __syncthreads();

        // ---- phase B: score_k = ||c_k||^2 - 2 z.c_k, packed-key argmin ----
        bf16x8 zb0 = *(const bf16x8*)(sXZ + row * 72 +  0 + lg * 8);
        bf16x8 zb1 = *(const bf16x8*)(sXZ + row * 72 + 32 + lg * 8);
        float runmin = INFINITY;
        #pragma unroll 4
        for (int ct = 0; ct < 32; ++ct) {
            f32x4 acc = *(const f32x4*)(sCbn + ct * 16 + klg);   // init = ||c||^2
            bf16x8 c0 = *(const bf16x8*)(sCbA + ((ct * 2 + 0) * 64 + l) * 8);
            bf16x8 c1 = *(const bf16x8*)(sCbA + ((ct * 2 + 1) * 64 + l) * 8);
            acc = __builtin_amdgcn_mfma_f32_16x16x32_bf16(c0, zb0, acc, 0, 0, 0);
            acc = __builtin_amdgcn_mfma_f32_16x16x32_bf16(c1, zb1, acc, 0, 0, 0);
            int kb = ct * 16 + klg;
            #pragma unroll
            for (int r = 0; r < 4; ++r) {
                // truncate low 9 mantissa bits, OR in code index: order-preserving
                // beyond 512-ulp near-ties (those are within tolerance either way)
                unsigned int key = (bcu(acc[r]) & 0xFFFFFE00u) | (unsigned int)(kb + r);
                runmin = fminf(runmin, bcf(key));
            }
        }
        float o = __shfl_xor(runmin, 16, 64); runmin = fminf(runmin, o);
        o = __shfl_xor(runmin, 32, 64);       runmin = fminf(runmin, o);
        const int kbest = (int)(bcu(runmin) & 511u);

        // ---- gather winner row (exact f32), store coalesced, loss ----
        const float* qrow = cb + (size_t)kbest * DDIM;   // L1/L2-hot
        const int pixg = pixbase + wv * 16 + p16;
        const int b2 = pixg >> 12;
        const int hw = pixg & 4095;
        float lsum = 0.f;
        #define OUTD(dt, za) { \
            _Pragma("unroll") \
            for (int r = 0; r < 4; ++r) { \
                int d = dt * 16 + klg + r; \
                float q = qrow[d]; \
                float e = q - za[r]; \
                lsum = fmaf(e, e, lsum); \
                out[((size_t)b2 * DDIM + d) * HWSZ + hw] = q; } }
        OUTD(0, za0) OUTD(1, za1) OUTD(2, za2) OUTD(3, za3)
        #undef OUTD

        #pragma unroll
        for (int off = 32; off > 0; off >>= 1)
            lsum += __shfl_down(lsum, off, 64);
        if (l == 0)
            atomicAdd(loss_slot, lsum * (1.25f / (float)NOUTQ));
        __syncthreads();   // zT reads done before next iter's xT staging
    }
}

extern "C" void kernel_launch(void* const* d_in, const int* in_sizes, int n_in,
                              void* d_out, int out_size, void* d_ws, size_t ws_size,
                              hipStream_t stream) {
    const float* x    = (const float*)d_in[0];   // [32,128,64,64]
    const float* w    = (const float*)d_in[1];   // [64,128]
    const float* bias = (const float*)d_in[2];   // [64]
    const float* cb   = (const float*)d_in[3];   // [512,64]
    float* out = (float*)d_out;                  // 8388608 quantized + 1 loss
    float* loss_slot = out + NOUTQ;

    vq_zero<<<1, 1, 0, stream>>>(loss_slot);
    vq_mfma<<<256, 1024, 0, stream>>>(x, w, bias, cb, out, loss_slot);
}

// Round 6
// 94.336 us; speedup vs baseline: 3.5490x; 1.4558x over previous
//
#include <hip/hip_runtime.h>
#include <hip/hip_bf16.h>
#include <math.h>

#define CIN   128
#define DDIM  64
#define KCB   512
#define HWSZ  4096
#define NPIX  131072
#define NOUTQ 8388608
#define XPAD  136   // shorts per pixel row in a wave's x/z slot (pad kills conflicts)

typedef short bf16x8 __attribute__((ext_vector_type(8)));
typedef float f32x4  __attribute__((ext_vector_type(4)));
typedef unsigned int u32x2 __attribute__((ext_vector_type(2)));

__device__ __forceinline__ unsigned int bcu(float f){ union{float f;unsigned int u;}v; v.f=f; return v.u; }
__device__ __forceinline__ float bcf(unsigned int u){ union{unsigned int u;float f;}v; v.u=u; return v.f; }
__device__ __forceinline__ unsigned int pkbf(float a, float b){   // 2xf32 -> packed bf16 (RNE)
    union { __hip_bfloat162 h; unsigned int u; } v;
    v.h = __float22bfloat162_rn(make_float2(a, b));
    return v.u;
}

// Zero the loss accumulator each call (harness poisons d_out once, never re-poisons).
__global__ void vq_zero(float* loss_slot) { *loss_slot = 0.f; }

// ---------------------------------------------------------------------------
// Per-wave independent tile pipeline. One tile = 16 pixels x 64 d.
//  cvt+write x -> own LDS slot; [prefetch next tile's x]; MFMA projection;
//  z round-trip through own slot (same-wave, no barrier); MFMA score scan
//  with packed-key argmin; gather winner (exact f32); store; loss accum.
// ---------------------------------------------------------------------------
template<bool PRE>
__device__ __forceinline__ void tile_body(
    float (&xr)[32], const float* preptr,
    unsigned short* slot, const unsigned short* sWA, const unsigned short* sCbA,
    const float* sCbn, const float* sBias,
    const float* __restrict__ cb, float* __restrict__ out, float& lsum,
    int b, int hwT, int p16, int lg, int klg, int l)
{
    // ---- x (f32 regs) -> bf16 -> slot row p16, c-block lg*32..lg*32+31 ----
    unsigned short* xrow = slot + p16 * XPAD;
    #pragma unroll
    for (int j = 0; j < 8; ++j) {
        u32x2 pv = { pkbf(xr[4*j+0], xr[4*j+1]), pkbf(xr[4*j+2], xr[4*j+3]) };
        *(u32x2*)(xrow + lg * 32 + 4 * j) = pv;   // ds_write_b64
    }
    if constexpr (PRE) {              // issue next tile's loads now (xr consumed)
        #pragma unroll
        for (int j = 0; j < 32; ++j) xr[j] = preptr[(size_t)j * HWSZ];
    }

    // ---- phase A: z = W x + b (16 MFMA), acc rows d = dt*16 + klg + r ----
    f32x4 za0 = *(const f32x4*)(sBias +  0 + klg);
    f32x4 za1 = *(const f32x4*)(sBias + 16 + klg);
    f32x4 za2 = *(const f32x4*)(sBias + 32 + klg);
    f32x4 za3 = *(const f32x4*)(sBias + 48 + klg);
    #pragma unroll
    for (int ks = 0; ks < 4; ++ks) {
        bf16x8 xf = *(const bf16x8*)(xrow + ks * 32 + lg * 8);
        bf16x8 w0 = *(const bf16x8*)(sWA + ((0 * 4 + ks) * 64 + l) * 8);
        bf16x8 w1 = *(const bf16x8*)(sWA + ((1 * 4 + ks) * 64 + l) * 8);
        bf16x8 w2 = *(const bf16x8*)(sWA + ((2 * 4 + ks) * 64 + l) * 8);
        bf16x8 w3 = *(const bf16x8*)(sWA + ((3 * 4 + ks) * 64 + l) * 8);
        za0 = __builtin_amdgcn_mfma_f32_16x16x32_bf16(w0, xf, za0, 0, 0, 0);
        za1 = __builtin_amdgcn_mfma_f32_16x16x32_bf16(w1, xf, za1, 0, 0, 0);
        za2 = __builtin_amdgcn_mfma_f32_16x16x32_bf16(w2, xf, za2, 0, 0, 0);
        za3 = __builtin_amdgcn_mfma_f32_16x16x32_bf16(w3, xf, za3, 0, 0, 0);
    }

    // ---- z -> bf16 -> same slot row (x reads already consumed; same-wave
    //      LDS ordering via lgkmcnt, no barrier) ----
    {
        unsigned int* zr = (unsigned int*)xrow;
        u32x2 z0 = { pkbf(za0[0], za0[1]), pkbf(za0[2], za0[3]) };
        u32x2 z1 = { pkbf(za1[0], za1[1]), pkbf(za1[2], za1[3]) };
        u32x2 z2 = { pkbf(za2[0], za2[1]), pkbf(za2[2], za2[3]) };
        u32x2 z3 = { pkbf(za3[0], za3[1]), pkbf(za3[2], za3[3]) };
        *(u32x2*)(zr +  0 + lg * 2) = z0;   // d = 0..15  (this lane: klg..klg+3)
        *(u32x2*)(zr +  8 + lg * 2) = z1;   // d = 16..31
        *(u32x2*)(zr + 16 + lg * 2) = z2;   // d = 32..47
        *(u32x2*)(zr + 24 + lg * 2) = z3;   // d = 48..63
    }
    bf16x8 zb0 = *(const bf16x8*)(xrow + lg * 8);        // d = lg*8 + e
    bf16x8 zb1 = *(const bf16x8*)(xrow + 32 + lg * 8);   // d = 32 + lg*8 + e

    // ---- phase B: score_k = ||c_k||^2 - 2 z.c_k; packed-key argmin ----
    float rm0 = INFINITY, rm1 = INFINITY;
    #pragma unroll 4
    for (int ct = 0; ct < 32; ++ct) {
        f32x4 acc = *(const f32x4*)(sCbn + ct * 16 + klg);   // init = ||c||^2
        bf16x8 c0 = *(const bf16x8*)(sCbA + ((ct * 2 + 0) * 64 + l) * 8);
        bf16x8 c1 = *(const bf16x8*)(sCbA + ((ct * 2 + 1) * 64 + l) * 8);
        acc = __builtin_amdgcn_mfma_f32_16x16x32_bf16(c0, zb0, acc, 0, 0, 0);
        acc = __builtin_amdgcn_mfma_f32_16x16x32_bf16(c1, zb1, acc, 0, 0, 0);
        unsigned int kb = (unsigned int)(ct * 16 + klg);
        rm0 = fminf(rm0, bcf((bcu(acc[0]) & 0xFFFFFE00u) | (kb + 0)));
        rm1 = fminf(rm1, bcf((bcu(acc[1]) & 0xFFFFFE00u) | (kb + 1)));
        rm0 = fminf(rm0, bcf((bcu(acc[2]) & 0xFFFFFE00u) | (kb + 2)));
        rm1 = fminf(rm1, bcf((bcu(acc[3]) & 0xFFFFFE00u) | (kb + 3)));
    }
    float runmin = fminf(rm0, rm1);
    runmin = fminf(runmin, __shfl_xor(runmin, 16, 64));
    runmin = fminf(runmin, __shfl_xor(runmin, 32, 64));
    const int kbest = (int)(bcu(runmin) & 511u);

    // ---- gather winner row (exact f32), store coalesced, loss partial ----
    const float* qrow = cb + (size_t)kbest * DDIM;   // L1/L2-hot
    size_t ob = ((size_t)b * DDIM + klg) * (size_t)HWSZ + hwT + p16;
    f32x4 q0 = *(const f32x4*)(qrow +  0 + klg);
    f32x4 q1 = *(const f32x4*)(qrow + 16 + klg);
    f32x4 q2 = *(const f32x4*)(qrow + 32 + klg);
    f32x4 q3 = *(const f32x4*)(qrow + 48 + klg);
    #pragma unroll
    for (int r = 0; r < 4; ++r) {
        float e0 = q0[r] - za0[r]; lsum = fmaf(e0, e0, lsum);
        float e1 = q1[r] - za1[r]; lsum = fmaf(e1, e1, lsum);
        float e2 = q2[r] - za2[r]; lsum = fmaf(e2, e2, lsum);
        float e3 = q3[r] - za3[r]; lsum = fmaf(e3, e3, lsum);
        out[ob + (size_t)(r +  0) * HWSZ] = q0[r];
        out[ob + (size_t)(r + 16) * HWSZ] = q1[r];
        out[ob + (size_t)(r + 32) * HWSZ] = q2[r];
        out[ob + (size_t)(r + 48) * HWSZ] = q3[r];
    }
}

__global__ __launch_bounds__(1024, 4) void vq_mfma(
    const float* __restrict__ x,      // [32][128][4096]
    const float* __restrict__ w,      // [64][128]
    const float* __restrict__ bias,   // [64]
    const float* __restrict__ cb,     // [512][64]
    float* __restrict__ out,          // [32][64][4096], loss at +NOUTQ
    float* __restrict__ loss_slot)
{
    __shared__ __align__(16) unsigned short sCbA[KCB * DDIM];   // 64 KB -2c A-frags
    __shared__ __align__(16) unsigned short sWA[DDIM * CIN];    // 16 KB W A-frags
    __shared__ __align__(16) float sCbn[KCB];                   // 2 KB
    __shared__ __align__(16) float sBias[DDIM];                 // 256 B
    __shared__ __align__(16) unsigned short sX[16 * 16 * XPAD]; // 68 KB wave slots

    const int t   = threadIdx.x;
    const int l   = t & 63;
    const int wv  = t >> 6;
    const int p16 = l & 15;
    const int lg  = l >> 4;
    const int klg = lg * 4;

    // ===== prologue: cooperative staging, packed b64 LDS writes =====
    #pragma unroll
    for (int it = 0; it < 8; ++it) {           // cb A-frags: A[k][d] = -2*cb
        int i = t + it * 1024;                 // (k, d-group of 4)
        int k = i >> 4, dg = i & 15;
        f32x4 v = *(const f32x4*)(cb + (size_t)k * DDIM + dg * 4);
        u32x2 pv = { pkbf(-2.f * v[0], -2.f * v[1]), pkbf(-2.f * v[2], -2.f * v[3]) };
        int ct = k >> 4, ks = dg >> 3, lhi = (dg >> 1) & 3, ll = (k & 15) | (lhi << 4);
        *(u32x2*)(sCbA + ((ct * 2 + ks) * 64 + ll) * 8 + (dg & 1) * 4) = pv;
    }
    #pragma unroll
    for (int it = 0; it < 2; ++it) {           // W A-frags: A[d][c]
        int i = t + it * 1024;                 // (d, c-group of 4)
        int d = i >> 5, cg = i & 31;
        f32x4 v = *(const f32x4*)(w + (size_t)d * CIN + cg * 4);
        u32x2 pv = { pkbf(v[0], v[1]), pkbf(v[2], v[3]) };
        int dt = d >> 4, ks = cg >> 3, lhi = (cg >> 1) & 3, ll = (d & 15) | (lhi << 4);
        *(u32x2*)(sWA + ((dt * 4 + ks) * 64 + ll) * 8 + (cg & 1) * 4) = pv;
    }
    if (t < KCB) {                             // ||c_k||^2 (f32, same FP order)
        const f32x4* row = (const f32x4*)(cb + (size_t)t * DDIM);
        float s = 0.f;
        #pragma unroll
        for (int j = 0; j < DDIM / 4; ++j) {
            f32x4 v = row[j];
            s = fmaf(v[0], v[0], s); s = fmaf(v[1], v[1], s);
            s = fmaf(v[2], v[2], s); s = fmaf(v[3], v[3], s);
        }
        sCbn[t] = s;
    }
    if (t < DDIM) sBias[t] = bias[t];
    __syncthreads();   // the ONLY barrier

    // ===== per-wave independent pipeline: 2 tiles of 16 pixels =====
    unsigned short* slot = sX + wv * (16 * XPAD);
    const int b   = blockIdx.x >> 3;                       // 512 pixels stay in one batch
    const int hw0 = (blockIdx.x & 7) * 512 + wv * 16;      // tile0 hw base
    const float* xp0 = x + ((size_t)b * CIN + (size_t)lg * 32) * HWSZ + hw0 + p16;

    float xr[32];
    #pragma unroll
    for (int j = 0; j < 32; ++j) xr[j] = xp0[(size_t)j * HWSZ];   // tile0 x

    float lsum = 0.f;
    tile_body<true >(xr, xp0 + 256, slot, sWA, sCbA, sCbn, sBias, cb, out, lsum,
                     b, hw0, p16, lg, klg, l);
    tile_body<false>(xr, nullptr, slot, sWA, sCbA, sCbn, sBias, cb, out, lsum,
                     b, hw0 + 256, p16, lg, klg, l);

    // one atomic per wave
    #pragma unroll
    for (int off = 32; off > 0; off >>= 1)
        lsum += __shfl_down(lsum, off, 64);
    if (l == 0)
        atomicAdd(loss_slot, lsum * (1.25f / (float)NOUTQ));
}

extern "C" void kernel_launch(void* const* d_in, const int* in_sizes, int n_in,
                              void* d_out, int out_size, void* d_ws, size_t ws_size,
                              hipStream_t stream) {
    const float* x    = (const float*)d_in[0];   // [32,128,64,64]
    const float* w    = (const float*)d_in[1];   // [64,128]
    const float* bias = (const float*)d_in[2];   // [64]
    const float* cb   = (const float*)d_in[3];   // [512,64]
    float* out = (float*)d_out;                  // 8388608 quantized + 1 loss
    float* loss_slot = out + NOUTQ;

    vq_zero<<<1, 1, 0, stream>>>(loss_slot);
    vq_mfma<<<256, 1024, 0, stream>>>(x, w, bias, cb, out, loss_slot);
}

// Round 7
// 49.285 us; speedup vs baseline: 6.7932x; 1.9141x over previous
//
#include <hip/hip_runtime.h>
#include <hip/hip_bf16.h>
#include <math.h>

#define CIN   128
#define DDIM  64
#define KCB   512
#define HWSZ  4096
#define NPIX  131072
#define NOUTQ 8388608
#define XPAD  136   // shorts per pixel row in a wave's x/z slot (pad kills conflicts)

typedef short bf16x8 __attribute__((ext_vector_type(8)));
typedef float f32x4  __attribute__((ext_vector_type(4)));
typedef unsigned int u32x2 __attribute__((ext_vector_type(2)));

__device__ __forceinline__ unsigned int bcu(float f){ union{float f;unsigned int u;}v; v.f=f; return v.u; }
__device__ __forceinline__ float bcf(unsigned int u){ union{unsigned int u;float f;}v; v.u=u; return v.f; }
__device__ __forceinline__ unsigned int pkbf(float a, float b){   // 2xf32 -> packed bf16 (RNE)
    union { __hip_bfloat162 h; unsigned int u; } v;
    v.h = __float22bfloat162_rn(make_float2(a, b));
    return v.u;
}

// Zero the loss accumulator each call (harness poisons d_out once, never re-poisons).
__global__ void vq_zero(float* loss_slot) { *loss_slot = 0.f; }

#define MFMA16(A, B, C) __builtin_amdgcn_mfma_f32_16x16x32_bf16((A), (B), (C), 0, 0, 0)

// stage x (regs->bf16->own slot), 16-MFMA projection, z roundtrip -> zb frags.
__device__ __forceinline__ void proj_tile(
    const float (&xr)[32], unsigned short* xrow,
    const unsigned short* sWA, const float* sBias,
    int lg, int klg, int l,
    f32x4& zA, f32x4& zB, f32x4& zC, f32x4& zD, bf16x8& zb0, bf16x8& zb1)
{
    #pragma unroll
    for (int j = 0; j < 8; ++j) {
        u32x2 pv = { pkbf(xr[4*j+0], xr[4*j+1]), pkbf(xr[4*j+2], xr[4*j+3]) };
        *(u32x2*)(xrow + lg * 32 + 4 * j) = pv;   // ds_write_b64
    }
    zA = *(const f32x4*)(sBias +  0 + klg);
    zB = *(const f32x4*)(sBias + 16 + klg);
    zC = *(const f32x4*)(sBias + 32 + klg);
    zD = *(const f32x4*)(sBias + 48 + klg);
    #pragma unroll
    for (int ks = 0; ks < 4; ++ks) {
        bf16x8 xf = *(const bf16x8*)(xrow + ks * 32 + lg * 8);
        bf16x8 w0 = *(const bf16x8*)(sWA + ((0 * 4 + ks) * 64 + l) * 8);
        bf16x8 w1 = *(const bf16x8*)(sWA + ((1 * 4 + ks) * 64 + l) * 8);
        bf16x8 w2 = *(const bf16x8*)(sWA + ((2 * 4 + ks) * 64 + l) * 8);
        bf16x8 w3 = *(const bf16x8*)(sWA + ((3 * 4 + ks) * 64 + l) * 8);
        zA = MFMA16(w0, xf, zA);
        zB = MFMA16(w1, xf, zB);
        zC = MFMA16(w2, xf, zC);
        zD = MFMA16(w3, xf, zD);
    }
    // z -> bf16 -> same row (same-wave LDS; compiler orders via lgkmcnt)
    unsigned int* zr = (unsigned int*)xrow;
    u32x2 z0 = { pkbf(zA[0], zA[1]), pkbf(zA[2], zA[3]) };
    u32x2 z1 = { pkbf(zB[0], zB[1]), pkbf(zB[2], zB[3]) };
    u32x2 z2 = { pkbf(zC[0], zC[1]), pkbf(zC[2], zC[3]) };
    u32x2 z3 = { pkbf(zD[0], zD[1]), pkbf(zD[2], zD[3]) };
    *(u32x2*)(zr +  0 + lg * 2) = z0;   // d = 0..15  (this lane: klg..klg+3)
    *(u32x2*)(zr +  8 + lg * 2) = z1;   // d = 16..31
    *(u32x2*)(zr + 16 + lg * 2) = z2;   // d = 32..47
    *(u32x2*)(zr + 24 + lg * 2) = z3;   // d = 48..63
    zb0 = *(const bf16x8*)(xrow + lg * 8);        // d = lg*8 + e
    zb1 = *(const bf16x8*)(xrow + 32 + lg * 8);   // d = 32 + lg*8 + e
}

// ---------------------------------------------------------------------------
// Per-wave independent dual-tile pipeline (32 adjacent pixels per wave):
// both tiles' x loaded upfront (full 128B lines per c-plane), projection per
// tile, then ONE codebook scan feeds both tiles (cb LDS reads halved).
// Loss: wave reduce -> LDS -> block reduce -> 1 atomic per block.
// ---------------------------------------------------------------------------
__global__ __launch_bounds__(1024, 4) void vq_mfma(
    const float* __restrict__ x,      // [32][128][4096]
    const float* __restrict__ w,      // [64][128]
    const float* __restrict__ bias,   // [64]
    const float* __restrict__ cb,     // [512][64]
    float* __restrict__ out,          // [32][64][4096], loss at +NOUTQ
    float* __restrict__ loss_slot)
{
    __shared__ __align__(16) unsigned short sCbA[KCB * DDIM];   // 64 KB -2c A-frags
    __shared__ __align__(16) unsigned short sWA[DDIM * CIN];    // 16 KB W A-frags
    __shared__ __align__(16) float sCbn[KCB];                   // 2 KB
    __shared__ __align__(16) float sBias[DDIM];                 // 256 B
    __shared__ __align__(16) unsigned short sX[16 * 16 * XPAD]; // 68 KB wave slots
    __shared__ float sLoss[16];

    const int t   = threadIdx.x;
    const int l   = t & 63;
    const int wv  = t >> 6;
    const int p16 = l & 15;
    const int lg  = l >> 4;
    const int klg = lg * 4;

    // ===== prologue: cooperative fragment staging (verified R5/R6) =====
    #pragma unroll
    for (int it = 0; it < 8; ++it) {           // cb A-frags: A[k][d] = -2*cb
        int i = t + it * 1024;
        int k = i >> 4, dg = i & 15;
        f32x4 v = *(const f32x4*)(cb + (size_t)k * DDIM + dg * 4);
        u32x2 pv = { pkbf(-2.f * v[0], -2.f * v[1]), pkbf(-2.f * v[2], -2.f * v[3]) };
        int ct = k >> 4, ks = dg >> 3, lhi = (dg >> 1) & 3, ll = (k & 15) | (lhi << 4);
        *(u32x2*)(sCbA + ((ct * 2 + ks) * 64 + ll) * 8 + (dg & 1) * 4) = pv;
    }
    #pragma unroll
    for (int it = 0; it < 2; ++it) {           // W A-frags: A[d][c]
        int i = t + it * 1024;
        int d = i >> 5, cg = i & 31;
        f32x4 v = *(const f32x4*)(w + (size_t)d * CIN + cg * 4);
        u32x2 pv = { pkbf(v[0], v[1]), pkbf(v[2], v[3]) };
        int dt = d >> 4, ks = cg >> 3, lhi = (cg >> 1) & 3, ll = (d & 15) | (lhi << 4);
        *(u32x2*)(sWA + ((dt * 4 + ks) * 64 + ll) * 8 + (cg & 1) * 4) = pv;
    }
    if (t < KCB) {                             // ||c_k||^2 (f32)
        const f32x4* row = (const f32x4*)(cb + (size_t)t * DDIM);
        float s = 0.f;
        #pragma unroll
        for (int j = 0; j < DDIM / 4; ++j) {
            f32x4 v = row[j];
            s = fmaf(v[0], v[0], s); s = fmaf(v[1], v[1], s);
            s = fmaf(v[2], v[2], s); s = fmaf(v[3], v[3], s);
        }
        sCbn[t] = s;
    }
    if (t < DDIM) sBias[t] = bias[t];
    __syncthreads();

    // ===== per-wave pipeline: 2 ADJACENT tiles (hw +0 / +16) =====
    unsigned short* xrow = sX + wv * (16 * XPAD) + p16 * XPAD;
    const int b   = blockIdx.x >> 3;
    const int hw0 = (blockIdx.x & 7) * 512 + wv * 32;
    const float* xp = x + ((size_t)b * CIN + (size_t)lg * 32) * HWSZ + hw0 + p16;

    float xr0[32], xr1[32];
    #pragma unroll
    for (int j = 0; j < 32; ++j) {             // paired: full 128B line per plane
        xr0[j] = xp[(size_t)j * HWSZ];
        xr1[j] = xp[(size_t)j * HWSZ + 16];
    }

    f32x4 zaA0, zaA1, zaA2, zaA3, zaB0, zaB1, zaB2, zaB3;
    bf16x8 zb00, zb01, zb10, zb11;
    proj_tile(xr0, xrow, sWA, sBias, lg, klg, l, zaA0, zaA1, zaA2, zaA3, zb00, zb01);
    proj_tile(xr1, xrow, sWA, sBias, lg, klg, l, zaB0, zaB1, zaB2, zaB3, zb10, zb11);

    // ---- phase B: one codebook scan, both tiles; packed-key argmin ----
    float rm00 = INFINITY, rm01 = INFINITY, rm10 = INFINITY, rm11 = INFINITY;
    #pragma unroll 4
    for (int ct = 0; ct < 32; ++ct) {
        f32x4 cinit = *(const f32x4*)(sCbn + ct * 16 + klg);   // init = ||c||^2
        bf16x8 c0 = *(const bf16x8*)(sCbA + ((ct * 2 + 0) * 64 + l) * 8);
        bf16x8 c1 = *(const bf16x8*)(sCbA + ((ct * 2 + 1) * 64 + l) * 8);
        f32x4 a0 = MFMA16(c0, zb00, cinit); a0 = MFMA16(c1, zb01, a0);
        f32x4 a1 = MFMA16(c0, zb10, cinit); a1 = MFMA16(c1, zb11, a1);
        unsigned int kb = (unsigned int)(ct * 16 + klg);
        rm00 = fminf(rm00, bcf((bcu(a0[0]) & 0xFFFFFE00u) | (kb + 0)));
        rm01 = fminf(rm01, bcf((bcu(a0[1]) & 0xFFFFFE00u) | (kb + 1)));
        rm00 = fminf(rm00, bcf((bcu(a0[2]) & 0xFFFFFE00u) | (kb + 2)));
        rm01 = fminf(rm01, bcf((bcu(a0[3]) & 0xFFFFFE00u) | (kb + 3)));
        rm10 = fminf(rm10, bcf((bcu(a1[0]) & 0xFFFFFE00u) | (kb + 0)));
        rm11 = fminf(rm11, bcf((bcu(a1[1]) & 0xFFFFFE00u) | (kb + 1)));
        rm10 = fminf(rm10, bcf((bcu(a1[2]) & 0xFFFFFE00u) | (kb + 2)));
        rm11 = fminf(rm11, bcf((bcu(a1[3]) & 0xFFFFFE00u) | (kb + 3)));
    }
    float rn0 = fminf(rm00, rm01);
    rn0 = fminf(rn0, __shfl_xor(rn0, 16, 64));
    rn0 = fminf(rn0, __shfl_xor(rn0, 32, 64));
    const int kbest0 = (int)(bcu(rn0) & 511u);
    float rn1 = fminf(rm10, rm11);
    rn1 = fminf(rn1, __shfl_xor(rn1, 16, 64));
    rn1 = fminf(rn1, __shfl_xor(rn1, 32, 64));
    const int kbest1 = (int)(bcu(rn1) & 511u);

    // ---- gather winners (exact f32), paired stores (128B line per plane) ----
    const float* q0r = cb + (size_t)kbest0 * DDIM;   // L2-hot
    const float* q1r = cb + (size_t)kbest1 * DDIM;
    f32x4 qa0 = *(const f32x4*)(q0r +  0 + klg), qb0 = *(const f32x4*)(q1r +  0 + klg);
    f32x4 qa1 = *(const f32x4*)(q0r + 16 + klg), qb1 = *(const f32x4*)(q1r + 16 + klg);
    f32x4 qa2 = *(const f32x4*)(q0r + 32 + klg), qb2 = *(const f32x4*)(q1r + 32 + klg);
    f32x4 qa3 = *(const f32x4*)(q0r + 48 + klg), qb3 = *(const f32x4*)(q1r + 48 + klg);
    float lsum = 0.f;
    size_t ob = ((size_t)b * DDIM + klg) * (size_t)HWSZ + hw0 + p16;
    #pragma unroll
    for (int r = 0; r < 4; ++r) {
        float e;
        e = qa0[r] - zaA0[r]; lsum = fmaf(e, e, lsum);
        e = qb0[r] - zaB0[r]; lsum = fmaf(e, e, lsum);
        e = qa1[r] - zaA1[r]; lsum = fmaf(e, e, lsum);
        e = qb1[r] - zaB1[r]; lsum = fmaf(e, e, lsum);
        e = qa2[r] - zaA2[r]; lsum = fmaf(e, e, lsum);
        e = qb2[r] - zaB2[r]; lsum = fmaf(e, e, lsum);
        e = qa3[r] - zaA3[r]; lsum = fmaf(e, e, lsum);
        e = qb3[r] - zaB3[r]; lsum = fmaf(e, e, lsum);
        out[ob + (size_t)(r +  0) * HWSZ]      = qa0[r];
        out[ob + (size_t)(r +  0) * HWSZ + 16] = qb0[r];
        out[ob + (size_t)(r + 16) * HWSZ]      = qa1[r];
        out[ob + (size_t)(r + 16) * HWSZ + 16] = qb1[r];
        out[ob + (size_t)(r + 32) * HWSZ]      = qa2[r];
        out[ob + (size_t)(r + 32) * HWSZ + 16] = qb2[r];
        out[ob + (size_t)(r + 48) * HWSZ]      = qa3[r];
        out[ob + (size_t)(r + 48) * HWSZ + 16] = qb3[r];
    }

    // ---- loss: wave reduce -> LDS -> block reduce -> ONE atomic per block ----
    #pragma unroll
    for (int off = 32; off > 0; off >>= 1)
        lsum += __shfl_down(lsum, off, 64);
    if (l == 0) sLoss[wv] = lsum;
    __syncthreads();
    if (wv == 0) {
        float v = (l < 16) ? sLoss[l] : 0.f;
        v += __shfl_down(v, 8, 64);
        v += __shfl_down(v, 4, 64);
        v += __shfl_down(v, 2, 64);
        v += __shfl_down(v, 1, 64);
        if (l == 0)
            atomicAdd(loss_slot, v * (1.25f / (float)NOUTQ));
    }
}

extern "C" void kernel_launch(void* const* d_in, const int* in_sizes, int n_in,
                              void* d_out, int out_size, void* d_ws, size_t ws_size,
                              hipStream_t stream) {
    const float* x    = (const float*)d_in[0];   // [32,128,64,64]
    const float* w    = (const float*)d_in[1];   // [64,128]
    const float* bias = (const float*)d_in[2];   // [64]
    const float* cb   = (const float*)d_in[3];   // [512,64]
    float* out = (float*)d_out;                  // 8388608 quantized + 1 loss
    float* loss_slot = out + NOUTQ;

    vq_zero<<<1, 1, 0, stream>>>(loss_slot);
    vq_mfma<<<256, 1024, 0, stream>>>(x, w, bias, cb, out, loss_slot);
}